// Round 4
// baseline (166.681 us; speedup 1.0000x reference)
//
#include <hip/hip_runtime.h>

// NonLocalBlock, B=4, C=64, H=W=64, N=4096, Ch=32.  MFMA f16, LDS-free hot loop.
//
// Index algebra (verified rounds 1-3):
//  x1[b,i,k] = conv1_flat[b][i*32+k]   (raw reshape of natural [ch][hw] buffer)
//  x2[b,k,j] = conv2 natural [k][j]
//  y3[b,j,c] = conv3_flat[b][j*32+c]
//  attn[b,i,j] = sum_k x1*x2 ; softmax over BATCH axis (4 elems, per (i,j))
//  O[b,i,c] = sum_j attn*y3 ;  y2[b,ch,hw] = O_flat[b][ch*4096+hw] -> conv4
//
// MFMA f16 16x16x32 layouts (HW-verified rounds 2-3):
//  A: A[m=lane&15][k=(lane>>4)*8+e]   B: B[k=(lane>>4)*8+e][n=lane&15]
//  C/D: row=(lane>>4)*4+reg, col=lane&15;  A-frag of M == B-frag of M^T.
// Stage 1 computes S^T with PERMUTED X2 rows (tile jh row m' -> j=(m'>>2)*8+jh*4+(m'&3))
// so lane (q,m) ends holding exactly the stage-2 B-frag P[i=m][k=q*8+e]. No transpose.
// Stage 2: O^T = mfma(A=Y3t rows (c), B=pfrag) -> 4 consecutive c per lane.

typedef _Float16 half8 __attribute__((ext_vector_type(8)));
typedef float f32x4 __attribute__((ext_vector_type(4)));

#define N_PIX 4096
#define NB    4
#define JS    4      // OP partial slices (blockIdx.y of attn)

// ws bytes: X1h @0 (1MB f16), X2t @1MB (1MB), Y3t @2MB (1MB), OP @3MB (8MB f32) = 11MB

// grid (128, 3): blockIdx.x = b*32 + chunk*2 + oh; weights via uniform (scalar) loads.
__global__ __launch_bounds__(256) void convs_kernel(
    const float* __restrict__ x,
    const float* __restrict__ w1, const float* __restrict__ b1,
    const float* __restrict__ w2, const float* __restrict__ b2,
    const float* __restrict__ w3, const float* __restrict__ b3,
    _Float16* __restrict__ X1h, _Float16* __restrict__ X2t, _Float16* __restrict__ Y3t)
{
    const int t = blockIdx.y;                  // which conv (0..2)
    const float* __restrict__ w  = (t == 0) ? w1 : ((t == 1) ? w2 : w3);
    const float* __restrict__ bb = (t == 0) ? b1 : ((t == 1) ? b2 : b3);

    __shared__ _Float16 sT[32 * 132];          // t==2 transpose tile (8.25 KB), stride 132

    const int tid   = threadIdx.x;
    const int b     = blockIdx.x >> 5;
    const int chunk = (blockIdx.x >> 1) & 15;
    const int oh    = blockIdx.x & 1;
    const int o0    = oh * 16;
    const int hw    = chunk * 256 + tid;

    float xi[64];
    const float* xb = x + b * 64 * N_PIX + hw;
    #pragma unroll
    for (int c = 0; c < 64; c++) xi[c] = xb[c * N_PIX];

    float acc[16];
    #pragma unroll
    for (int oo = 0; oo < 16; oo++) {
        const int o = o0 + oo;
        // w[o*64+c], bb[o] are loop-uniform -> scalar loads (SGPR), no LDS
        float a0 = bb[o], a1 = 0.f, a2 = 0.f, a3 = 0.f;
        #pragma unroll
        for (int c = 0; c < 64; c += 4) {
            a0 += xi[c + 0] * w[o * 64 + c + 0];
            a1 += xi[c + 1] * w[o * 64 + c + 1];
            a2 += xi[c + 2] * w[o * 64 + c + 2];
            a3 += xi[c + 3] * w[o * 64 + c + 3];
        }
        acc[oo] = (a0 + a1) + (a2 + a3);
    }

    if (t == 0) {
        // X1h natural flat [ch][hw]  (== [i][k] under raw reshape)
        #pragma unroll
        for (int oo = 0; oo < 16; oo++)
            X1h[b * 131072 + (o0 + oo) * N_PIX + hw] = (_Float16)acc[oo];
    } else if (t == 1) {
        // X2t[b][j=hw][k=ch]: 16 contiguous f16 per thread (two half8)
        #pragma unroll
        for (int mc = 0; mc < 2; mc++) {
            half8 v;
            #pragma unroll
            for (int e = 0; e < 8; e++) v[e] = (_Float16)acc[mc * 8 + e];
            *(half8*)&X2t[b * 131072 + hw * 32 + o0 + mc * 8] = v;
        }
    } else {
        // Y3t[b][c][j], element acc[oo]: c = hw&31, j = (o0+oo)*128 + (hw>>5).
        // Stage through LDS so global stores are contiguous half8.
        const int c  = tid & 31;
        const int jl = tid >> 5;               // 0..7
        #pragma unroll
        for (int oo = 0; oo < 16; oo++)
            sT[c * 132 + oo * 8 + jl] = (_Float16)acc[oo];
        __syncthreads();
        const int jb0 = chunk * 8;             // base (hw>>5) for this block
        #pragma unroll
        for (int g = 0; g < 2; g++) {
            int u   = g * 256 + tid;           // 0..511 = c2*16 ... use c2 = u&31, oo2 = u>>5
            int c2  = u & 31;
            int oo2 = u >> 5;                  // 0..15
            half8 v = *(half8*)&sT[c2 * 132 + oo2 * 8];
            *(half8*)&Y3t[b * 131072 + c2 * 4096 + (o0 + oo2) * 128 + jb0] = v;
        }
    }
}

// grid (256, JS): blockIdx.x = i-tile (16 rows), blockIdx.y = j-split.
// Wave wv covers j in [js*1024 + wv*256, +256), 8 iters of 32.
__global__ __launch_bounds__(256) void attn_kernel(
    const _Float16* __restrict__ X1h, const _Float16* __restrict__ X2t,
    const _Float16* __restrict__ Y3t, float* __restrict__ OP)
{
    __shared__ float sRed[4 * 32 * 64];        // [wave][f][lane], 32 KB

    const int tid  = threadIdx.x;
    const int wv   = tid >> 6;
    const int lane = tid & 63;
    const int m    = lane & 15;
    const int q    = lane >> 4;
    const int i0   = blockIdx.x * 16;
    const int js   = blockIdx.y;
    const int jbase = js * 1024 + wv * 256;

    // stage-1 B-frags: x1[i0+m][k=q*8..] per batch (A-frag data of x1)
    half8 bx1[NB];
    #pragma unroll
    for (int b = 0; b < NB; b++)
        bx1[b] = *(const half8*)&X1h[b * 131072 + (i0 + m) * 32 + q * 8];

    f32x4 oaccT[NB][2];                        // [b][ch], lane: O^T[c][i]
    #pragma unroll
    for (int b = 0; b < NB; b++) {
        oaccT[b][0] = (f32x4){0.f, 0.f, 0.f, 0.f};
        oaccT[b][1] = (f32x4){0.f, 0.f, 0.f, 0.f};
    }

    const int jrow0 = ((m >> 2) * 8) + (m & 3);   // permuted A-row base (+ jh*4)

    for (int jt = 0; jt < 8; jt++) {
        const int j0 = jbase + jt * 32;

        // fragment loads (no LDS)
        half8 ax2[NB][2], ay3[NB][2];
        #pragma unroll
        for (int b = 0; b < NB; b++) {
            #pragma unroll
            for (int jh = 0; jh < 2; jh++)
                ax2[b][jh] = *(const half8*)&X2t[b * 131072 + (j0 + jrow0 + jh * 4) * 32 + q * 8];
            #pragma unroll
            for (int ch = 0; ch < 2; ch++)
                ay3[b][ch] = *(const half8*)&Y3t[b * 131072 + (ch * 16 + m) * 4096 + j0 + q * 8];
        }

        // stage 1: S^T tiles (permuted rows)
        f32x4 sT[NB][2];
        #pragma unroll
        for (int b = 0; b < NB; b++)
            #pragma unroll
            for (int jh = 0; jh < 2; jh++)
                sT[b][jh] = __builtin_amdgcn_mfma_f32_16x16x32_f16(
                    ax2[b][jh], bx1[b], (f32x4){0.f, 0.f, 0.f, 0.f}, 0, 0, 0);

        // softmax over batch (register-local), pack stage-2 B-frag in-lane
        half8 pf[NB];
        #pragma unroll
        for (int jh = 0; jh < 2; jh++)
            #pragma unroll
            for (int r = 0; r < 4; r++) {
                float s0 = sT[0][jh][r], s1 = sT[1][jh][r];
                float s2 = sT[2][jh][r], s3 = sT[3][jh][r];
                float mx = fmaxf(fmaxf(s0, s1), fmaxf(s2, s3));
                float e0 = __expf(s0 - mx), e1 = __expf(s1 - mx);
                float e2 = __expf(s2 - mx), e3 = __expf(s3 - mx);
                float rs = __builtin_amdgcn_rcpf(e0 + e1 + e2 + e3);
                pf[0][jh * 4 + r] = (_Float16)(e0 * rs);
                pf[1][jh * 4 + r] = (_Float16)(e1 * rs);
                pf[2][jh * 4 + r] = (_Float16)(e2 * rs);
                pf[3][jh * 4 + r] = (_Float16)(e3 * rs);
            }

        // stage 2: O^T += Y3^T x P^T
        #pragma unroll
        for (int b = 0; b < NB; b++)
            #pragma unroll
            for (int ch = 0; ch < 2; ch++)
                oaccT[b][ch] = __builtin_amdgcn_mfma_f32_16x16x32_f16(
                    ay3[b][ch], pf[b], oaccT[b][ch], 0, 0, 0);
    }

    // cross-wave reduction (4 j-subchunks -> one OP slice). f = b*8+ch*4+r.
    #pragma unroll
    for (int b = 0; b < NB; b++)
        #pragma unroll
        for (int ch = 0; ch < 2; ch++)
            #pragma unroll
            for (int r = 0; r < 4; r++)
                sRed[(wv * 32 + b * 8 + ch * 4 + r) * 64 + lane] = oaccT[b][ch][r];
    __syncthreads();

    const int br = wv;                         // wave writes batch b=wv
    float* op = OP + js * 524288 + (br * 4096 + i0) * 32;
    #pragma unroll
    for (int ch = 0; ch < 2; ch++) {
        f32x4 v;
        #pragma unroll
        for (int r = 0; r < 4; r++) {
            int f = br * 8 + ch * 4 + r;
            v[r] = sRed[(0 * 32 + f) * 64 + lane] + sRed[(1 * 32 + f) * 64 + lane]
                 + sRed[(2 * 32 + f) * 64 + lane] + sRed[(3 * 32 + f) * 64 + lane];
        }
        *(f32x4*)&op[m * 32 + ch * 16 + q * 4] = v;
    }
}

// grid (64, 4): reduce JS partials + conv4 (scalar weights).
__global__ __launch_bounds__(256) void out_kernel(
    const float* __restrict__ OP, const float* __restrict__ w4,
    const float* __restrict__ b4, float* __restrict__ out)
{
    const int tid = threadIdx.x;
    const int b   = blockIdx.x >> 4;
    const int hw  = ((blockIdx.x & 15) << 8) + tid;
    const int o0  = blockIdx.y * 16;

    float y2[32];
    #pragma unroll
    for (int ch = 0; ch < 32; ch++) {
        float v = 0.f;
        #pragma unroll
        for (int p = 0; p < JS; p++)
            v += OP[p * 524288 + b * 131072 + ch * 4096 + hw];   // coalesced
        y2[ch] = v;
    }

    float* ob = out + b * 64 * N_PIX + hw;
    #pragma unroll
    for (int oo = 0; oo < 16; oo++) {
        const int o = o0 + oo;
        float a0 = b4[o], a1 = 0.f, a2 = 0.f, a3 = 0.f;
        #pragma unroll
        for (int c = 0; c < 32; c += 4) {
            a0 += y2[c + 0] * w4[o * 32 + c + 0];
            a1 += y2[c + 1] * w4[o * 32 + c + 1];
            a2 += y2[c + 2] * w4[o * 32 + c + 2];
            a3 += y2[c + 3] * w4[o * 32 + c + 3];
        }
        ob[o * N_PIX] = (a0 + a1) + (a2 + a3);
    }
}

extern "C" void kernel_launch(void* const* d_in, const int* in_sizes, int n_in,
                              void* d_out, int out_size, void* d_ws, size_t ws_size,
                              hipStream_t stream) {
    const float* x  = (const float*)d_in[0];
    const float* w1 = (const float*)d_in[1];
    const float* b1 = (const float*)d_in[2];
    const float* w2 = (const float*)d_in[3];
    const float* b2 = (const float*)d_in[4];
    const float* w3 = (const float*)d_in[5];
    const float* b3 = (const float*)d_in[6];
    const float* w4 = (const float*)d_in[7];
    const float* b4 = (const float*)d_in[8];

    char* wsb = (char*)d_ws;
    _Float16* X1h = (_Float16*)(wsb);
    _Float16* X2t = (_Float16*)(wsb + (1 << 20));
    _Float16* Y3t = (_Float16*)(wsb + (2 << 20));
    float*    OP  = (float*)   (wsb + (3 << 20));   // JS x 2MB
    float*    out = (float*)d_out;

    dim3 g1(128, 3);
    convs_kernel<<<g1, 256, 0, stream>>>(x, w1, b1, w2, b2, w3, b3, X1h, X2t, Y3t);
    dim3 g2(256, JS);
    attn_kernel<<<g2, 256, 0, stream>>>(X1h, X2t, Y3t, OP);
    dim3 g3(64, 4);
    out_kernel<<<g3, 256, 0, stream>>>(OP, w4, b4, out);
}